// Round 4
// baseline (335.956 us; speedup 1.0000x reference)
//
#include <hip/hip_runtime.h>
#include <hip/hip_fp16.h>

// Problem constants (match reference)
#define IN_CH   128
#define HC      64      // channels per node at every layer boundary
#define NEG_SLOPE 0.2f

// counting-sort parameters: bucket = dst >> BSH (<=512 buckets), src in low 17 bits
#define BSH   8
#define NPB   256       // nodes per bucket = 1 << BSH
#define EPB   4096      // edges per binning block
#define DBIN  64        // degree bins for node degree-sort (clamped)

typedef __attribute__((ext_vector_type(8))) _Float16 f16x8;
typedef __attribute__((ext_vector_type(4))) float    f32x4;

// ---------------------------------------------------------------------------
// Fused W pre-pack (all 3 layers, one launch) + zero-init of histogram arrays.
// fp32 W[K][64] -> fp16 B-fragment order for mfma_f32_16x16x32_f16.
// zeroz[0..575] = bcnt[512] ++ dcnt[64], zeroed here (runs before csortA1).
// ---------------------------------------------------------------------------
__global__ __launch_bounds__(256) void wpack3_k(const float* __restrict__ W1, const float* __restrict__ W2,
                                                const float* __restrict__ W3, _Float16* __restrict__ P1,
                                                _Float16* __restrict__ P2, _Float16* __restrict__ P3,
                                                int* __restrict__ zeroz) {
    int o = blockIdx.x * 256 + threadIdx.x;    // grid covers 16384 = 8192+4096+4096
    if (o < 576) zeroz[o] = 0;
    const float* W; _Float16* P; int oo;
    if (o < 8192)       { W = W1; P = P1; oo = o; }
    else if (o < 12288) { W = W2; P = P2; oo = o - 8192; }
    else                { W = W3; P = P3; oo = o - 12288; }
    int j = oo & 7, l = (oo >> 3) & 63, t = (oo >> 9) & 3, s = oo >> 11;
    int row = s * 32 + ((l >> 4) << 3) + j;
    int col = (t << 4) + (l & 15);
    P[oo] = (_Float16)W[row * 64 + col];
}

// ---------------------------------------------------------------------------
// counting sort of edges by dst bucket — atomic-reservation scheme.
// A1: LDS histogram -> global bucket counts (bcnt) AND per-block cache (countsT).
// ---------------------------------------------------------------------------
__global__ __launch_bounds__(256) void csortA1_k(const int* __restrict__ ei, int* __restrict__ bcnt,
                                                 int* __restrict__ countsT, int E) {
    __shared__ int cnt[512];
    int tid = threadIdx.x;
    cnt[tid] = 0; cnt[tid + 256] = 0;
    __syncthreads();
    int base = blockIdx.x * EPB;
#pragma unroll
    for (int k = 0; k < EPB / 256; k++) {
        int i = base + k * 256 + tid;
        if (i < E) atomicAdd(&cnt[ei[E + i] >> BSH], 1);
    }
    __syncthreads();
#pragma unroll
    for (int r = 0; r < 2; r++) {
        int b = r * 256 + tid;
        int c = cnt[b];
        countsT[blockIdx.x * 512 + b] = c;   // cache for A3 (incl. zeros)
        if (c) atomicAdd(&bcnt[b], c);
    }
}

// one block: exclusive scan of 512 bucket counts -> bucket bases + write cursors
__global__ __launch_bounds__(512) void bscan_k(const int* __restrict__ bcnt, int* __restrict__ bbase,
                                               int* __restrict__ bcur, int nbuck, int E) {
    __shared__ int s[512];
    int tid = threadIdx.x;
    int v = bcnt[tid];                      // zeros beyond nbuck
    s[tid] = v; __syncthreads();
    for (int o = 1; o < 512; o <<= 1) {
        int t = (tid >= o) ? s[tid - o] : 0;
        __syncthreads();
        s[tid] += t;
        __syncthreads();
    }
    int ex = s[tid] - v;
    if (tid < nbuck) { bbase[tid] = ex; bcur[tid] = ex; }
    if (tid == 0) bbase[nbuck] = E;
}

// A3: read cached per-block counts -> reserve per-bucket output range via one
// global atomicAdd per (block,bucket) -> write pairs through LDS cursors.
__global__ __launch_bounds__(256) void csortA3_k(const int* __restrict__ ei, const int* __restrict__ countsT,
                                                 int* __restrict__ bcur, unsigned* __restrict__ pairs, int E) {
    __shared__ int cur[512];
    int tid = threadIdx.x;
#pragma unroll
    for (int r = 0; r < 2; r++) {
        int b = r * 256 + tid;
        int c = countsT[blockIdx.x * 512 + b];
        cur[b] = c ? atomicAdd(&bcur[b], c) : 0;
    }
    __syncthreads();
    int base = blockIdx.x * EPB;
#pragma unroll
    for (int k = 0; k < EPB / 256; k++) {
        int i = base + k * 256 + tid;
        if (i < E) {
            int d = ei[E + i];
            int s = ei[i];
            int p = atomicAdd(&cur[d >> BSH], 1);
            pairs[p] = ((unsigned)(d & (NPB - 1)) << 17) | (unsigned)s;
        }
    }
}

// B: one block per bucket (256 nodes/bucket, 1 node/thread). Fused: per-node LDS
// histogram -> block scan -> node offsets (off[]) -> LDS-cursor ranking -> csr
// write. Zero-pads csr[E..E+63]. Also folds the global degree-bin histogram.
__global__ __launch_bounds__(256) void csortB2_k(const unsigned* __restrict__ pairs, const int* __restrict__ bbase,
                                                 int* __restrict__ off, int* __restrict__ csr,
                                                 int* __restrict__ dcnt, int N, int E, int nbuck) {
    __shared__ int cnt[NPB];
    __shared__ int cur[NPB];
    __shared__ int ps[256];
    __shared__ int dh[DBIN];
    int b = blockIdx.x;
    int tid = threadIdx.x;
    int rs = bbase[b];
    int re = bbase[b + 1];

    cnt[tid] = 0;
    if (tid < DBIN) dh[tid] = 0;
    __syncthreads();
    for (int j = rs + tid; j < re; j += 256)
        atomicAdd(&cnt[pairs[j] >> 17], 1);
    __syncthreads();

    int c0 = cnt[tid];
    int n0 = b * NPB + tid;
    if (n0 < N) atomicAdd(&dh[min(c0, DBIN - 1)], 1);
    ps[tid] = c0;
    __syncthreads();
    for (int o = 1; o < 256; o <<= 1) {
        int t = (tid >= o) ? ps[tid - o] : 0;
        __syncthreads();
        ps[tid] += t;
        __syncthreads();
    }
    int base0 = rs + ps[tid] - c0;
    cur[tid] = base0;
    if (n0 < N) off[n0] = base0;
    if (b == nbuck - 1 && tid == 0) off[N] = E;
    if (b == nbuck - 1 && tid < 64) csr[E + tid] = 0;   // pad for batched reads
    __syncthreads();
    if (tid < DBIN && dh[tid]) atomicAdd(&dcnt[tid], dh[tid]);

    for (int j = rs + tid; j < re; j += 256) {
        unsigned v = pairs[j];
        int p = atomicAdd(&cur[v >> 17], 1);
        csr[p] = (int)(v & 0x1FFFF);
    }
}

// ---------------------------------------------------------------------------
// Node degree-sort: tiny 1-wave scan of the 64-bin histogram, then
// reserve-and-rank (one block per 256-node bucket, re-derives degrees from off).
// ---------------------------------------------------------------------------
__global__ void dscan_k(const int* __restrict__ dcnt, int* __restrict__ dcur) {
    __shared__ int s[DBIN];
    int tid = threadIdx.x;
    int v = dcnt[tid];
    s[tid] = v; __syncthreads();
    for (int o = 1; o < DBIN; o <<= 1) {
        int t = (tid >= o) ? s[tid - o] : 0;
        __syncthreads();
        s[tid] += t;
        __syncthreads();
    }
    dcur[tid] = s[tid] - v;
}

__global__ __launch_bounds__(256) void drank2_k(const int* __restrict__ off, int* __restrict__ dcur,
                                                int* __restrict__ perm, int N) {
    __shared__ int h[DBIN];
    __shared__ int cur[DBIN];
    int b = blockIdx.x, tid = threadIdx.x;
    if (tid < DBIN) h[tid] = 0;
    __syncthreads();
    int n0 = b * 256 + tid;
    int d0 = -1;
    if (n0 < N) { d0 = min(off[n0 + 1] - off[n0], DBIN - 1); atomicAdd(&h[d0], 1); }
    __syncthreads();
    if (tid < DBIN) cur[tid] = h[tid] ? atomicAdd(&dcur[tid], h[tid]) : 0;
    __syncthreads();
    if (n0 < N) perm[atomicAdd(&cur[d0], 1)] = n0;
}

// ---------------------------------------------------------------------------
// MFMA GEMM: H[n,64] = X[n,K] @ W[K,64] + logits epilogue.
// F16IN: X is fp16 (layer 2/3, direct A-frag 16B loads, no cvt).
// ---------------------------------------------------------------------------
template<int K, int HEADS, bool F16IN>
__global__ __launch_bounds__(256) void gemm_mfma_k(const void* __restrict__ Xv, const _Float16* __restrict__ P,
                                                   const float* __restrict__ a_s, const float* __restrict__ a_d,
                                                   __half* __restrict__ H, float* __restrict__ ALS,
                                                   float* __restrict__ ALD, int n) {
    __shared__ _Float16 lh[4][16 * 72];   // per-wave transpose buffer, stride 72 halves
    int tid = threadIdx.x;
    int wv = tid >> 6, lane = tid & 63;
    int wid = blockIdx.x * 4 + wv;
    int rowbase = wid << 4;
    if (rowbase >= n) return;
    int q = lane >> 4, cl = lane & 15;

    f16x8 b[K / 32][4];
    const f16x8* Pv = (const f16x8*)P;
#pragma unroll
    for (int s = 0; s < K / 32; s++)
#pragma unroll
        for (int t = 0; t < 4; t++)
            b[s][t] = Pv[(s * 4 + t) * 64 + lane];

    f32x4 c[4];
#pragma unroll
    for (int t = 0; t < 4; t++) c[t] = (f32x4){0.f, 0.f, 0.f, 0.f};

#pragma unroll
    for (int s = 0; s < K / 32; s++) {
        f16x8 a;
        if (F16IN) {
            const _Float16* xrow = (const _Float16*)Xv + (size_t)(rowbase + cl) * K + q * 8;
            a = *(const f16x8*)(xrow + s * 32);
        } else {
            const float* xrow = (const float*)Xv + (size_t)(rowbase + cl) * K + q * 8;
            float4 x0 = *(const float4*)(xrow + s * 32);
            float4 x1 = *(const float4*)(xrow + s * 32 + 4);
            a[0] = (_Float16)x0.x; a[1] = (_Float16)x0.y; a[2] = (_Float16)x0.z; a[3] = (_Float16)x0.w;
            a[4] = (_Float16)x1.x; a[5] = (_Float16)x1.y; a[6] = (_Float16)x1.z; a[7] = (_Float16)x1.w;
        }
#pragma unroll
        for (int t = 0; t < 4; t++)
            c[t] = __builtin_amdgcn_mfma_f32_16x16x32_f16(a, b[s][t], c[t], 0, 0, 0);
    }

    if (HEADS == 2) {
        float as0 = a_s[cl], as1 = a_s[16 + cl], as2 = a_s[32 + cl], as3 = a_s[48 + cl];
        float ad0 = a_d[cl], ad1 = a_d[16 + cl], ad2 = a_d[32 + cl], ad3 = a_d[48 + cl];
#pragma unroll
        for (int reg = 0; reg < 4; reg++) {
            float s0 = c[0][reg] * as0 + c[1][reg] * as1;
            float d0 = c[0][reg] * ad0 + c[1][reg] * ad1;
            float s1 = c[2][reg] * as2 + c[3][reg] * as3;
            float d1 = c[2][reg] * ad2 + c[3][reg] * ad3;
#pragma unroll
            for (int m = 1; m <= 8; m <<= 1) {
                s0 += __shfl_xor(s0, m, 64);
                d0 += __shfl_xor(d0, m, 64);
                s1 += __shfl_xor(s1, m, 64);
                d1 += __shfl_xor(d1, m, 64);
            }
            if (cl == 0) {
                int row = rowbase + q * 4 + reg;
                ALS[row * 2]     = s0;
                ALS[row * 2 + 1] = s1;
                ALD[row * 2]     = d0;
                ALD[row * 2 + 1] = d1;
            }
        }
    } else {
        float as0 = a_s[cl], as1 = a_s[16 + cl], as2 = a_s[32 + cl], as3 = a_s[48 + cl];
        float ad0 = a_d[cl], ad1 = a_d[16 + cl], ad2 = a_d[32 + cl], ad3 = a_d[48 + cl];
#pragma unroll
        for (int reg = 0; reg < 4; reg++) {
            float s0 = c[0][reg] * as0 + c[1][reg] * as1 + c[2][reg] * as2 + c[3][reg] * as3;
            float d0 = c[0][reg] * ad0 + c[1][reg] * ad1 + c[2][reg] * ad2 + c[3][reg] * ad3;
#pragma unroll
            for (int m = 1; m <= 8; m <<= 1) {
                s0 += __shfl_xor(s0, m, 64);
                d0 += __shfl_xor(d0, m, 64);
            }
            if (cl == 0) {
                int row = rowbase + q * 4 + reg;
                ALS[row] = s0;
                ALD[row] = d0;
            }
        }
    }

    _Float16* L = lh[wv];
#pragma unroll
    for (int t = 0; t < 4; t++)
#pragma unroll
        for (int reg = 0; reg < 4; reg++)
            L[(q * 4 + reg) * 72 + t * 16 + cl] = (_Float16)c[t][reg];
    __builtin_amdgcn_s_waitcnt(0);
    int rr = lane >> 2, seg = lane & 3;
    uint4 v0 = *(const uint4*)((const char*)L + rr * 144 + seg * 32);
    uint4 v1 = *(const uint4*)((const char*)L + rr * 144 + seg * 32 + 16);
    char* hb = (char*)(H + (size_t)rowbase * 64);
    *(uint4*)(hb + rr * 128 + seg * 32)      = v0;
    *(uint4*)(hb + rr * 128 + seg * 32 + 16) = v1;
}

// ---------------------------------------------------------------------------
// Aggregation: 8 NODES PER WAVE (8 lanes/node, 8 ch/lane via 16B uint4 loads),
// degree-sorted node assignment; SOFTWARE-PIPELINED 8-deep batches (double
// register buffer: load batch b+1 while consuming batch b); csr 64-entry pad.
// OUTF16: write fp16 (layer boundary — identical rounding to gemm's own cvt).
// ---------------------------------------------------------------------------
template<int HEADS, int RELU, bool OUTF16>
__global__ __launch_bounds__(256) void aggregate_k(const __half* __restrict__ H, const float* __restrict__ ALS,
                                                   const float* __restrict__ ALD, const int* __restrict__ off,
                                                   const int* __restrict__ csr, const int* __restrict__ perm,
                                                   const float* __restrict__ bias, void* __restrict__ OUT, int n) {
    int lane = threadIdx.x & 63;
    int wv   = threadIdx.x >> 6;
    int c8   = lane & 7;                  // channel octet: channels 8c8 .. 8c8+7
    int idx  = blockIdx.x * 32 + wv * 8 + (lane >> 3);
    bool alive = idx < n;
    int dst = perm[alive ? idx : 0];
    int head = (HEADS == 2) ? (c8 >> 2) : 0;

    int b0 = off[dst];
    int len = alive ? (off[dst + 1] - b0) : 0;
    float ald = ALD[dst * HEADS + head];

    // self-loop contribution
    float e = ALS[dst * HEADS + head] + ald;
    e = fmaxf(e, NEG_SLOPE * e);
    float ee = alive ? __expf(e) : 0.f;
    float den = ee;
    const uint4* Ho = (const uint4*)H;    // H row = 8 uint4 (64 halfs)
    uint4 hv = Ho[dst * 8 + c8];
    float acc[8];
    {
        float2 p0 = __half22float2(*(const __half2*)&hv.x);
        float2 p1 = __half22float2(*(const __half2*)&hv.y);
        float2 p2 = __half22float2(*(const __half2*)&hv.z);
        float2 p3 = __half22float2(*(const __half2*)&hv.w);
        acc[0] = ee * p0.x; acc[1] = ee * p0.y; acc[2] = ee * p1.x; acc[3] = ee * p1.y;
        acc[4] = ee * p2.x; acc[5] = ee * p2.y; acc[6] = ee * p3.x; acc[7] = ee * p3.y;
    }

    int lmax = max(len, __shfl_xor(len, 8, 64));
    lmax = max(lmax, __shfl_xor(lmax, 16, 64));
    lmax = max(lmax, __shfl_xor(lmax, 32, 64));   // wave-uniform

    // batch load: 2x int4 index load (csr pad makes one-batch-ahead safe),
    // then 8 ALS + 8 H gathers into named register buffers (static indexing).
    auto LOADB = [&](int jbase, float* al, uint4* h) {
        int i0 = b0 + jbase;
        int4 sa = *(const int4*)(csr + i0);
        int4 sb = *(const int4*)(csr + i0 + 4);
        int s0 = sa.x, s1 = sa.y, s2 = sa.z, s3 = sa.w;
        int s4 = sb.x, s5 = sb.y, s6 = sb.z, s7 = sb.w;
        al[0] = ALS[s0 * HEADS + head]; al[1] = ALS[s1 * HEADS + head];
        al[2] = ALS[s2 * HEADS + head]; al[3] = ALS[s3 * HEADS + head];
        al[4] = ALS[s4 * HEADS + head]; al[5] = ALS[s5 * HEADS + head];
        al[6] = ALS[s6 * HEADS + head]; al[7] = ALS[s7 * HEADS + head];
        h[0] = Ho[s0 * 8 + c8]; h[1] = Ho[s1 * 8 + c8];
        h[2] = Ho[s2 * 8 + c8]; h[3] = Ho[s3 * 8 + c8];
        h[4] = Ho[s4 * 8 + c8]; h[5] = Ho[s5 * 8 + c8];
        h[6] = Ho[s6 * 8 + c8]; h[7] = Ho[s7 * 8 + c8];
    };
    auto CONS = [&](const float* al, const uint4* h, int jbase) {
#pragma unroll
        for (int k = 0; k < 8; k++) {
            float ek = al[k] + ald;
            ek = fmaxf(ek, NEG_SLOPE * ek);
            float wk = (jbase + k < len) ? __expf(ek) : 0.f;
            den += wk;
            float2 p0 = __half22float2(*(const __half2*)&h[k].x);
            float2 p1 = __half22float2(*(const __half2*)&h[k].y);
            float2 p2 = __half22float2(*(const __half2*)&h[k].z);
            float2 p3 = __half22float2(*(const __half2*)&h[k].w);
            acc[0] += wk * p0.x; acc[1] += wk * p0.y; acc[2] += wk * p1.x; acc[3] += wk * p1.y;
            acc[4] += wk * p2.x; acc[5] += wk * p2.y; acc[6] += wk * p3.x; acc[7] += wk * p3.y;
        }
    };

    int nb = lmax >> 3;                   // full 8-edge batches (wave-uniform)
    if (nb) {
        float alA[8], alB[8];
        uint4 hA[8], hB[8];
        LOADB(0, alA, hA);
        int b = 0;
        for (;;) {
            if (b + 1 < nb) LOADB((b + 1) << 3, alB, hB);   // prefetch next
            CONS(alA, hA, b << 3);
            if (++b == nb) break;
            if (b + 1 < nb) LOADB((b + 1) << 3, alA, hA);
            CONS(alB, hB, b << 3);
            if (++b == nb) break;
        }
    }
    for (int j = nb << 3; j < lmax; j++) {
        int s0 = csr[b0 + j];
        float alv = ALS[s0 * HEADS + head];
        uint4 h0 = Ho[s0 * 8 + c8];
        float e0 = alv + ald;
        e0 = fmaxf(e0, NEG_SLOPE * e0);
        float w0 = (j < len) ? __expf(e0) : 0.f;
        den += w0;
        float2 p0 = __half22float2(*(const __half2*)&h0.x);
        float2 p1 = __half22float2(*(const __half2*)&h0.y);
        float2 p2 = __half22float2(*(const __half2*)&h0.z);
        float2 p3 = __half22float2(*(const __half2*)&h0.w);
        acc[0] += w0 * p0.x; acc[1] += w0 * p0.y; acc[2] += w0 * p1.x; acc[3] += w0 * p1.y;
        acc[4] += w0 * p2.x; acc[5] += w0 * p2.y; acc[6] += w0 * p3.x; acc[7] += w0 * p3.y;
    }

    if (alive) {
        float4 b0v = ((const float4*)bias)[2 * c8];
        float4 b1v = ((const float4*)bias)[2 * c8 + 1];
        float rd = 1.f / den;
        float o[8];
        o[0] = acc[0] * rd + b0v.x; o[1] = acc[1] * rd + b0v.y;
        o[2] = acc[2] * rd + b0v.z; o[3] = acc[3] * rd + b0v.w;
        o[4] = acc[4] * rd + b1v.x; o[5] = acc[5] * rd + b1v.y;
        o[6] = acc[6] * rd + b1v.z; o[7] = acc[7] * rd + b1v.w;
        if (RELU) {
#pragma unroll
            for (int k = 0; k < 8; k++) o[k] = fmaxf(o[k], 0.f);
        }
        if (OUTF16) {
            __half2 q0 = __floats2half2_rn(o[0], o[1]);
            __half2 q1 = __floats2half2_rn(o[2], o[3]);
            __half2 q2 = __floats2half2_rn(o[4], o[5]);
            __half2 q3 = __floats2half2_rn(o[6], o[7]);
            uint4 u;
            u.x = *(unsigned*)&q0; u.y = *(unsigned*)&q1;
            u.z = *(unsigned*)&q2; u.w = *(unsigned*)&q3;
            ((uint4*)OUT)[dst * 8 + c8] = u;
        } else {
            ((float4*)OUT)[dst * 16 + 2 * c8]     = make_float4(o[0], o[1], o[2], o[3]);
            ((float4*)OUT)[dst * 16 + 2 * c8 + 1] = make_float4(o[4], o[5], o[6], o[7]);
        }
    }
}

// ---------------------------------------------------------------------------
extern "C" void kernel_launch(void* const* d_in, const int* in_sizes, int n_in,
                              void* d_out, int out_size, void* d_ws, size_t ws_size,
                              hipStream_t stream) {
    const float* x   = (const float*)d_in[0];
    const int*   ei  = (const int*)  d_in[1];
    const float* W1  = (const float*)d_in[2];
    const float* as1 = (const float*)d_in[3];
    const float* ad1 = (const float*)d_in[4];
    const float* b1  = (const float*)d_in[5];
    const float* W2  = (const float*)d_in[6];
    const float* as2 = (const float*)d_in[7];
    const float* ad2 = (const float*)d_in[8];
    const float* b2  = (const float*)d_in[9];
    const float* W3  = (const float*)d_in[10];
    const float* as3 = (const float*)d_in[11];
    const float* ad3 = (const float*)d_in[12];
    const float* b3  = (const float*)d_in[13];

    const int N = in_sizes[0] / IN_CH;
    const int E = in_sizes[1] / 2;
    const int NBUCK = (N + NPB - 1) >> BSH;              // 391 (<=512)
    const int NEB   = (E + EPB - 1) / EPB;               // 391 binning blocks

    // workspace carve (256B aligned)
    char* p = (char*)d_ws;
    auto carve = [&](size_t bytes) {
        char* r = p;
        p += (bytes + 255) & ~(size_t)255;
        return r;
    };
    __half*    hbuf    = (__half*)   carve((size_t)N * HC * 2);
    __half*    obuf    = (__half*)   carve((size_t)N * HC * 2);   // fp16 layer boundary
    float*     als     = (float*)    carve((size_t)N * 2 * 4);
    float*     ald     = (float*)    carve((size_t)N * 2 * 4);
    int*       off     = (int*)      carve((size_t)(N + 1) * 4);
    int*       csr     = (int*)      carve((size_t)(E + 64) * 4);   // +64 zero pad
    unsigned*  pairs   = (unsigned*) carve((size_t)E * 4);
    int*       bcnt    = (int*)      carve((size_t)576 * 4);        // bcnt[512] ++ dcnt[64]
    int*       dcnt    = bcnt + 512;
    int*       bbase   = (int*)      carve((size_t)520 * 4);        // NBUCK+1
    int*       bcur    = (int*)      carve((size_t)512 * 4);
    int*       dcur    = (int*)      carve((size_t)DBIN * 4);
    int*       perm    = (int*)      carve((size_t)N * 4);
    int*       countsT = (int*)      carve((size_t)NEB * 512 * 4);  // per-block bucket counts
    _Float16*  wp1     = (_Float16*) carve((size_t)IN_CH * 64 * 2);
    _Float16*  wp2     = (_Float16*) carve((size_t)64 * 64 * 2);
    _Float16*  wp3     = (_Float16*) carve((size_t)64 * 64 * 2);

    const int NW8 = (N + 31) / 32;        // aggregate: 8 nodes/wave, 4 waves/block
    const int NBM = (N / 16 + 3) / 4;     // mfma gemm: 16 rows/wave, 4 waves/block

    // ---- W fragment pre-pack (all layers) + zero-init bcnt/dcnt ----
    wpack3_k<<<64, 256, 0, stream>>>(W1, W2, W3, wp1, wp2, wp3, bcnt);

    // ---- CSR build (shared by all 3 layers); atomic-reservation sort ----
    csortA1_k<<<NEB, 256, 0, stream>>>(ei, bcnt, countsT, E);
    bscan_k  <<<1, 512, 0, stream>>>(bcnt, bbase, bcur, NBUCK, E);
    csortA3_k<<<NEB, 256, 0, stream>>>(ei, countsT, bcur, pairs, E);
    csortB2_k<<<NBUCK, 256, 0, stream>>>(pairs, bbase, off, csr, dcnt, N, E, NBUCK);

    // ---- node degree-sort (for aggregate wave load balance) ----
    dscan_k  <<<1, DBIN, 0, stream>>>(dcnt, dcur);
    drank2_k <<<NBUCK, 256, 0, stream>>>(off, dcur, perm, N);

    // ---- Layer 1: IN=128 -> 2x32 concat, relu ----
    gemm_mfma_k<128, 2, false><<<NBM, 256, 0, stream>>>(x, wp1, as1, ad1, hbuf, als, ald, N);
    aggregate_k<2, 1, true>   <<<NW8, 256, 0, stream>>>(hbuf, als, ald, off, csr, perm, b1, obuf, N);

    // ---- Layer 2: 64 -> 2x32 concat, relu ----
    gemm_mfma_k<64, 2, true><<<NBM, 256, 0, stream>>>(obuf, wp2, as2, ad2, hbuf, als, ald, N);
    aggregate_k<2, 1, true> <<<NW8, 256, 0, stream>>>(hbuf, als, ald, off, csr, perm, b2, obuf, N);

    // ---- Layer 3: 64 -> 64, 1 head, mean(=identity), no relu ----
    gemm_mfma_k<64, 1, true><<<NBM, 256, 0, stream>>>(obuf, wp3, as3, ad3, hbuf, als, ald, N);
    aggregate_k<1, 0, false><<<NW8, 256, 0, stream>>>(hbuf, als, ald, off, csr, perm, b3, d_out, N);
}

// Round 5
// 327.043 us; speedup vs baseline: 1.0273x; 1.0273x over previous
//
#include <hip/hip_runtime.h>
#include <hip/hip_fp16.h>

// Problem constants (match reference)
#define IN_CH   128
#define HC      64      // channels per node at every layer boundary
#define NEG_SLOPE 0.2f

// counting-sort parameters: bucket = dst >> BSH (<=512 buckets), src in low 17 bits
#define BSH   8
#define NPB   256       // nodes per bucket = 1 << BSH
#define EPB   4096      // edges per binning block
#define DBIN  64        // degree bins for node degree-sort (clamped)

typedef __attribute__((ext_vector_type(8))) _Float16 f16x8;
typedef __attribute__((ext_vector_type(4))) float    f32x4;

// ---------------------------------------------------------------------------
// Fused W pre-pack (all 3 layers, one launch) + zero-init of histogram arrays.
// fp32 W[K][64] -> fp16 B-fragment order for mfma_f32_16x16x32_f16.
// zeroz[0..575] = bcnt[512] ++ dcnt[64], zeroed here (runs before csortA1).
// ---------------------------------------------------------------------------
__global__ __launch_bounds__(256) void wpack3_k(const float* __restrict__ W1, const float* __restrict__ W2,
                                                const float* __restrict__ W3, _Float16* __restrict__ P1,
                                                _Float16* __restrict__ P2, _Float16* __restrict__ P3,
                                                int* __restrict__ zeroz) {
    int o = blockIdx.x * 256 + threadIdx.x;    // grid covers 16384 = 8192+4096+4096
    if (o < 576) zeroz[o] = 0;
    const float* W; _Float16* P; int oo;
    if (o < 8192)       { W = W1; P = P1; oo = o; }
    else if (o < 12288) { W = W2; P = P2; oo = o - 8192; }
    else                { W = W3; P = P3; oo = o - 12288; }
    int j = oo & 7, l = (oo >> 3) & 63, t = (oo >> 9) & 3, s = oo >> 11;
    int row = s * 32 + ((l >> 4) << 3) + j;
    int col = (t << 4) + (l & 15);
    P[oo] = (_Float16)W[row * 64 + col];
}

// ---------------------------------------------------------------------------
// counting sort of edges by dst bucket — atomic-reservation scheme.
// A1: LDS histogram -> global bucket counts (bcnt) AND per-block cache (countsT).
// ---------------------------------------------------------------------------
__global__ __launch_bounds__(256) void csortA1_k(const int* __restrict__ ei, int* __restrict__ bcnt,
                                                 int* __restrict__ countsT, int E) {
    __shared__ int cnt[512];
    int tid = threadIdx.x;
    cnt[tid] = 0; cnt[tid + 256] = 0;
    __syncthreads();
    int base = blockIdx.x * EPB;
#pragma unroll
    for (int k = 0; k < EPB / 256; k++) {
        int i = base + k * 256 + tid;
        if (i < E) atomicAdd(&cnt[ei[E + i] >> BSH], 1);
    }
    __syncthreads();
#pragma unroll
    for (int r = 0; r < 2; r++) {
        int b = r * 256 + tid;
        int c = cnt[b];
        countsT[blockIdx.x * 512 + b] = c;   // cache for A3 (incl. zeros)
        if (c) atomicAdd(&bcnt[b], c);
    }
}

// one block: exclusive scan of 512 bucket counts -> bucket bases + write cursors
__global__ __launch_bounds__(512) void bscan_k(const int* __restrict__ bcnt, int* __restrict__ bbase,
                                               int* __restrict__ bcur, int nbuck, int E) {
    __shared__ int s[512];
    int tid = threadIdx.x;
    int v = bcnt[tid];                      // zeros beyond nbuck
    s[tid] = v; __syncthreads();
    for (int o = 1; o < 512; o <<= 1) {
        int t = (tid >= o) ? s[tid - o] : 0;
        __syncthreads();
        s[tid] += t;
        __syncthreads();
    }
    int ex = s[tid] - v;
    if (tid < nbuck) { bbase[tid] = ex; bcur[tid] = ex; }
    if (tid == 0) bbase[nbuck] = E;
}

// A3: read cached per-block counts -> reserve per-bucket output range via one
// global atomicAdd per (block,bucket) -> write pairs through LDS cursors.
__global__ __launch_bounds__(256) void csortA3_k(const int* __restrict__ ei, const int* __restrict__ countsT,
                                                 int* __restrict__ bcur, unsigned* __restrict__ pairs, int E) {
    __shared__ int cur[512];
    int tid = threadIdx.x;
#pragma unroll
    for (int r = 0; r < 2; r++) {
        int b = r * 256 + tid;
        int c = countsT[blockIdx.x * 512 + b];
        cur[b] = c ? atomicAdd(&bcur[b], c) : 0;
    }
    __syncthreads();
    int base = blockIdx.x * EPB;
#pragma unroll
    for (int k = 0; k < EPB / 256; k++) {
        int i = base + k * 256 + tid;
        if (i < E) {
            int d = ei[E + i];
            int s = ei[i];
            int p = atomicAdd(&cur[d >> BSH], 1);
            pairs[p] = ((unsigned)(d & (NPB - 1)) << 17) | (unsigned)s;
        }
    }
}

// B: one block per bucket (256 nodes/bucket, 1 node/thread). Fused: per-node LDS
// histogram -> block scan -> node offsets (off[]) -> LDS-cursor ranking -> csr
// write. Zero-pads csr[E..E+63]. Also folds the global degree-bin histogram.
__global__ __launch_bounds__(256) void csortB2_k(const unsigned* __restrict__ pairs, const int* __restrict__ bbase,
                                                 int* __restrict__ off, int* __restrict__ csr,
                                                 int* __restrict__ dcnt, int N, int E, int nbuck) {
    __shared__ int cnt[NPB];
    __shared__ int cur[NPB];
    __shared__ int ps[256];
    __shared__ int dh[DBIN];
    int b = blockIdx.x;
    int tid = threadIdx.x;
    int rs = bbase[b];
    int re = bbase[b + 1];

    cnt[tid] = 0;
    if (tid < DBIN) dh[tid] = 0;
    __syncthreads();
    for (int j = rs + tid; j < re; j += 256)
        atomicAdd(&cnt[pairs[j] >> 17], 1);
    __syncthreads();

    int c0 = cnt[tid];
    int n0 = b * NPB + tid;
    if (n0 < N) atomicAdd(&dh[min(c0, DBIN - 1)], 1);
    ps[tid] = c0;
    __syncthreads();
    for (int o = 1; o < 256; o <<= 1) {
        int t = (tid >= o) ? ps[tid - o] : 0;
        __syncthreads();
        ps[tid] += t;
        __syncthreads();
    }
    int base0 = rs + ps[tid] - c0;
    cur[tid] = base0;
    if (n0 < N) off[n0] = base0;
    if (b == nbuck - 1 && tid == 0) off[N] = E;
    if (b == nbuck - 1 && tid < 64) csr[E + tid] = 0;   // pad for batched reads
    __syncthreads();
    if (tid < DBIN && dh[tid]) atomicAdd(&dcnt[tid], dh[tid]);

    for (int j = rs + tid; j < re; j += 256) {
        unsigned v = pairs[j];
        int p = atomicAdd(&cur[v >> 17], 1);
        csr[p] = (int)(v & 0x1FFFF);
    }
}

// ---------------------------------------------------------------------------
// Node degree-sort. LPT ordering: DESCENDING degree (suffix-sum bases), so the
// heaviest blocks dispatch FIRST and light blocks backfill — kills the tail
// where few heavy blocks hold the whole grid.
// ---------------------------------------------------------------------------
__global__ void dscan_k(const int* __restrict__ dcnt, int* __restrict__ dcur) {
    __shared__ int s[DBIN];
    int tid = threadIdx.x;
    int v = dcnt[tid];
    s[tid] = v; __syncthreads();
    for (int o = 1; o < DBIN; o <<= 1) {
        int t = (tid >= o) ? s[tid - o] : 0;
        __syncthreads();
        s[tid] += t;
        __syncthreads();
    }
    // s[tid] = inclusive prefix (ascending). Descending-degree base:
    // bin d starts after all bins with larger degree: total - incl[d].
    dcur[tid] = s[DBIN - 1] - s[tid];
}

__global__ __launch_bounds__(256) void drank2_k(const int* __restrict__ off, int* __restrict__ dcur,
                                                int* __restrict__ perm, int N) {
    __shared__ int h[DBIN];
    __shared__ int cur[DBIN];
    int b = blockIdx.x, tid = threadIdx.x;
    if (tid < DBIN) h[tid] = 0;
    __syncthreads();
    int n0 = b * 256 + tid;
    int d0 = -1;
    if (n0 < N) { d0 = min(off[n0 + 1] - off[n0], DBIN - 1); atomicAdd(&h[d0], 1); }
    __syncthreads();
    if (tid < DBIN) cur[tid] = h[tid] ? atomicAdd(&dcur[tid], h[tid]) : 0;
    __syncthreads();
    if (n0 < N) perm[atomicAdd(&cur[d0], 1)] = n0;
}

// ---------------------------------------------------------------------------
// MFMA GEMM: H[n,64] = X[n,K] @ W[K,64] + logits epilogue.
// F16IN: X is fp16 (layer 2/3, direct A-frag 16B loads, no cvt).
// ---------------------------------------------------------------------------
template<int K, int HEADS, bool F16IN>
__global__ __launch_bounds__(256) void gemm_mfma_k(const void* __restrict__ Xv, const _Float16* __restrict__ P,
                                                   const float* __restrict__ a_s, const float* __restrict__ a_d,
                                                   __half* __restrict__ H, float* __restrict__ ALS,
                                                   float* __restrict__ ALD, int n) {
    __shared__ _Float16 lh[4][16 * 72];   // per-wave transpose buffer, stride 72 halves
    int tid = threadIdx.x;
    int wv = tid >> 6, lane = tid & 63;
    int wid = blockIdx.x * 4 + wv;
    int rowbase = wid << 4;
    if (rowbase >= n) return;
    int q = lane >> 4, cl = lane & 15;

    f16x8 b[K / 32][4];
    const f16x8* Pv = (const f16x8*)P;
#pragma unroll
    for (int s = 0; s < K / 32; s++)
#pragma unroll
        for (int t = 0; t < 4; t++)
            b[s][t] = Pv[(s * 4 + t) * 64 + lane];

    f32x4 c[4];
#pragma unroll
    for (int t = 0; t < 4; t++) c[t] = (f32x4){0.f, 0.f, 0.f, 0.f};

#pragma unroll
    for (int s = 0; s < K / 32; s++) {
        f16x8 a;
        if (F16IN) {
            const _Float16* xrow = (const _Float16*)Xv + (size_t)(rowbase + cl) * K + q * 8;
            a = *(const f16x8*)(xrow + s * 32);
        } else {
            const float* xrow = (const float*)Xv + (size_t)(rowbase + cl) * K + q * 8;
            float4 x0 = *(const float4*)(xrow + s * 32);
            float4 x1 = *(const float4*)(xrow + s * 32 + 4);
            a[0] = (_Float16)x0.x; a[1] = (_Float16)x0.y; a[2] = (_Float16)x0.z; a[3] = (_Float16)x0.w;
            a[4] = (_Float16)x1.x; a[5] = (_Float16)x1.y; a[6] = (_Float16)x1.z; a[7] = (_Float16)x1.w;
        }
#pragma unroll
        for (int t = 0; t < 4; t++)
            c[t] = __builtin_amdgcn_mfma_f32_16x16x32_f16(a, b[s][t], c[t], 0, 0, 0);
    }

    if (HEADS == 2) {
        float as0 = a_s[cl], as1 = a_s[16 + cl], as2 = a_s[32 + cl], as3 = a_s[48 + cl];
        float ad0 = a_d[cl], ad1 = a_d[16 + cl], ad2 = a_d[32 + cl], ad3 = a_d[48 + cl];
#pragma unroll
        for (int reg = 0; reg < 4; reg++) {
            float s0 = c[0][reg] * as0 + c[1][reg] * as1;
            float d0 = c[0][reg] * ad0 + c[1][reg] * ad1;
            float s1 = c[2][reg] * as2 + c[3][reg] * as3;
            float d1 = c[2][reg] * ad2 + c[3][reg] * ad3;
#pragma unroll
            for (int m = 1; m <= 8; m <<= 1) {
                s0 += __shfl_xor(s0, m, 64);
                d0 += __shfl_xor(d0, m, 64);
                s1 += __shfl_xor(s1, m, 64);
                d1 += __shfl_xor(d1, m, 64);
            }
            if (cl == 0) {
                int row = rowbase + q * 4 + reg;
                ALS[row * 2]     = s0;
                ALS[row * 2 + 1] = s1;
                ALD[row * 2]     = d0;
                ALD[row * 2 + 1] = d1;
            }
        }
    } else {
        float as0 = a_s[cl], as1 = a_s[16 + cl], as2 = a_s[32 + cl], as3 = a_s[48 + cl];
        float ad0 = a_d[cl], ad1 = a_d[16 + cl], ad2 = a_d[32 + cl], ad3 = a_d[48 + cl];
#pragma unroll
        for (int reg = 0; reg < 4; reg++) {
            float s0 = c[0][reg] * as0 + c[1][reg] * as1 + c[2][reg] * as2 + c[3][reg] * as3;
            float d0 = c[0][reg] * ad0 + c[1][reg] * ad1 + c[2][reg] * ad2 + c[3][reg] * ad3;
#pragma unroll
            for (int m = 1; m <= 8; m <<= 1) {
                s0 += __shfl_xor(s0, m, 64);
                d0 += __shfl_xor(d0, m, 64);
            }
            if (cl == 0) {
                int row = rowbase + q * 4 + reg;
                ALS[row] = s0;
                ALD[row] = d0;
            }
        }
    }

    _Float16* L = lh[wv];
#pragma unroll
    for (int t = 0; t < 4; t++)
#pragma unroll
        for (int reg = 0; reg < 4; reg++)
            L[(q * 4 + reg) * 72 + t * 16 + cl] = (_Float16)c[t][reg];
    __builtin_amdgcn_s_waitcnt(0);
    int rr = lane >> 2, seg = lane & 3;
    uint4 v0 = *(const uint4*)((const char*)L + rr * 144 + seg * 32);
    uint4 v1 = *(const uint4*)((const char*)L + rr * 144 + seg * 32 + 16);
    char* hb = (char*)(H + (size_t)rowbase * 64);
    *(uint4*)(hb + rr * 128 + seg * 32)      = v0;
    *(uint4*)(hb + rr * 128 + seg * 32 + 16) = v1;
}

// ---------------------------------------------------------------------------
// Aggregation: 8 NODES PER WAVE (8 lanes/node, 8 ch/lane via 16B uint4 loads),
// degree-sorted node assignment; 8-deep batches; csr 64-entry zero pad.
// (R3 loop restored — R4's explicit 2-deep register pipeline REGRESSED:
//  VGPR 52->68, occupancy -5pt, +2.7us/layer. TLP covers the latency here.)
// OUTF16: write fp16 (layer boundary — identical rounding to gemm's own cvt).
// ---------------------------------------------------------------------------
template<int HEADS, int RELU, bool OUTF16>
__global__ __launch_bounds__(256) void aggregate_k(const __half* __restrict__ H, const float* __restrict__ ALS,
                                                   const float* __restrict__ ALD, const int* __restrict__ off,
                                                   const int* __restrict__ csr, const int* __restrict__ perm,
                                                   const float* __restrict__ bias, void* __restrict__ OUT, int n) {
    int lane = threadIdx.x & 63;
    int wv   = threadIdx.x >> 6;
    int c8   = lane & 7;                  // channel octet: channels 8c8 .. 8c8+7
    int idx  = blockIdx.x * 32 + wv * 8 + (lane >> 3);
    bool alive = idx < n;
    int dst = perm[alive ? idx : 0];
    int head = (HEADS == 2) ? (c8 >> 2) : 0;

    int b0 = off[dst];
    int len = alive ? (off[dst + 1] - b0) : 0;
    float ald = ALD[dst * HEADS + head];

    // self-loop contribution
    float e = ALS[dst * HEADS + head] + ald;
    e = fmaxf(e, NEG_SLOPE * e);
    float ee = alive ? __expf(e) : 0.f;
    float den = ee;
    const uint4* Ho = (const uint4*)H;    // H row = 8 uint4 (64 halfs)
    uint4 hv = Ho[dst * 8 + c8];
    float acc[8];
    {
        float2 p0 = __half22float2(*(const __half2*)&hv.x);
        float2 p1 = __half22float2(*(const __half2*)&hv.y);
        float2 p2 = __half22float2(*(const __half2*)&hv.z);
        float2 p3 = __half22float2(*(const __half2*)&hv.w);
        acc[0] = ee * p0.x; acc[1] = ee * p0.y; acc[2] = ee * p1.x; acc[3] = ee * p1.y;
        acc[4] = ee * p2.x; acc[5] = ee * p2.y; acc[6] = ee * p3.x; acc[7] = ee * p3.y;
    }

    int lmax = max(len, __shfl_xor(len, 8, 64));
    lmax = max(lmax, __shfl_xor(lmax, 16, 64));
    lmax = max(lmax, __shfl_xor(lmax, 32, 64));

    int j = 0;
    for (; j + 7 < lmax; j += 8) {
        int i0 = b0 + j;
        int s[8];
#pragma unroll
        for (int k = 0; k < 8; k++) s[k] = csr[i0 + k];      // padded: always safe
        float al[8];
#pragma unroll
        for (int k = 0; k < 8; k++) al[k] = ALS[s[k] * HEADS + head];
        uint4 h[8];
#pragma unroll
        for (int k = 0; k < 8; k++) h[k] = Ho[s[k] * 8 + c8];
#pragma unroll
        for (int k = 0; k < 8; k++) {
            float ek = al[k] + ald;
            ek = fmaxf(ek, NEG_SLOPE * ek);
            float wk = (j + k < len) ? __expf(ek) : 0.f;
            den += wk;
            float2 p0 = __half22float2(*(const __half2*)&h[k].x);
            float2 p1 = __half22float2(*(const __half2*)&h[k].y);
            float2 p2 = __half22float2(*(const __half2*)&h[k].z);
            float2 p3 = __half22float2(*(const __half2*)&h[k].w);
            acc[0] += wk * p0.x; acc[1] += wk * p0.y; acc[2] += wk * p1.x; acc[3] += wk * p1.y;
            acc[4] += wk * p2.x; acc[5] += wk * p2.y; acc[6] += wk * p3.x; acc[7] += wk * p3.y;
        }
    }
    for (; j < lmax; j++) {
        int s0 = csr[b0 + j];
        float alv = ALS[s0 * HEADS + head];
        uint4 h0 = Ho[s0 * 8 + c8];
        float e0 = alv + ald;
        e0 = fmaxf(e0, NEG_SLOPE * e0);
        float w0 = (j < len) ? __expf(e0) : 0.f;
        den += w0;
        float2 p0 = __half22float2(*(const __half2*)&h0.x);
        float2 p1 = __half22float2(*(const __half2*)&h0.y);
        float2 p2 = __half22float2(*(const __half2*)&h0.z);
        float2 p3 = __half22float2(*(const __half2*)&h0.w);
        acc[0] += w0 * p0.x; acc[1] += w0 * p0.y; acc[2] += w0 * p1.x; acc[3] += w0 * p1.y;
        acc[4] += w0 * p2.x; acc[5] += w0 * p2.y; acc[6] += w0 * p3.x; acc[7] += w0 * p3.y;
    }

    if (alive) {
        float4 b0v = ((const float4*)bias)[2 * c8];
        float4 b1v = ((const float4*)bias)[2 * c8 + 1];
        float rd = 1.f / den;
        float o[8];
        o[0] = acc[0] * rd + b0v.x; o[1] = acc[1] * rd + b0v.y;
        o[2] = acc[2] * rd + b0v.z; o[3] = acc[3] * rd + b0v.w;
        o[4] = acc[4] * rd + b1v.x; o[5] = acc[5] * rd + b1v.y;
        o[6] = acc[6] * rd + b1v.z; o[7] = acc[7] * rd + b1v.w;
        if (RELU) {
#pragma unroll
            for (int k = 0; k < 8; k++) o[k] = fmaxf(o[k], 0.f);
        }
        if (OUTF16) {
            __half2 q0 = __floats2half2_rn(o[0], o[1]);
            __half2 q1 = __floats2half2_rn(o[2], o[3]);
            __half2 q2 = __floats2half2_rn(o[4], o[5]);
            __half2 q3 = __floats2half2_rn(o[6], o[7]);
            uint4 u;
            u.x = *(unsigned*)&q0; u.y = *(unsigned*)&q1;
            u.z = *(unsigned*)&q2; u.w = *(unsigned*)&q3;
            ((uint4*)OUT)[dst * 8 + c8] = u;
        } else {
            ((float4*)OUT)[dst * 16 + 2 * c8]     = make_float4(o[0], o[1], o[2], o[3]);
            ((float4*)OUT)[dst * 16 + 2 * c8 + 1] = make_float4(o[4], o[5], o[6], o[7]);
        }
    }
}

// ---------------------------------------------------------------------------
extern "C" void kernel_launch(void* const* d_in, const int* in_sizes, int n_in,
                              void* d_out, int out_size, void* d_ws, size_t ws_size,
                              hipStream_t stream) {
    const float* x   = (const float*)d_in[0];
    const int*   ei  = (const int*)  d_in[1];
    const float* W1  = (const float*)d_in[2];
    const float* as1 = (const float*)d_in[3];
    const float* ad1 = (const float*)d_in[4];
    const float* b1  = (const float*)d_in[5];
    const float* W2  = (const float*)d_in[6];
    const float* as2 = (const float*)d_in[7];
    const float* ad2 = (const float*)d_in[8];
    const float* b2  = (const float*)d_in[9];
    const float* W3  = (const float*)d_in[10];
    const float* as3 = (const float*)d_in[11];
    const float* ad3 = (const float*)d_in[12];
    const float* b3  = (const float*)d_in[13];

    const int N = in_sizes[0] / IN_CH;
    const int E = in_sizes[1] / 2;
    const int NBUCK = (N + NPB - 1) >> BSH;              // 391 (<=512)
    const int NEB   = (E + EPB - 1) / EPB;               // 391 binning blocks

    // workspace carve (256B aligned)
    char* p = (char*)d_ws;
    auto carve = [&](size_t bytes) {
        char* r = p;
        p += (bytes + 255) & ~(size_t)255;
        return r;
    };
    __half*    hbuf    = (__half*)   carve((size_t)N * HC * 2);
    __half*    obuf    = (__half*)   carve((size_t)N * HC * 2);   // fp16 layer boundary
    float*     als     = (float*)    carve((size_t)N * 2 * 4);
    float*     ald     = (float*)    carve((size_t)N * 2 * 4);
    int*       off     = (int*)      carve((size_t)(N + 1) * 4);
    int*       csr     = (int*)      carve((size_t)(E + 64) * 4);   // +64 zero pad
    unsigned*  pairs   = (unsigned*) carve((size_t)E * 4);
    int*       bcnt    = (int*)      carve((size_t)576 * 4);        // bcnt[512] ++ dcnt[64]
    int*       dcnt    = bcnt + 512;
    int*       bbase   = (int*)      carve((size_t)520 * 4);        // NBUCK+1
    int*       bcur    = (int*)      carve((size_t)512 * 4);
    int*       dcur    = (int*)      carve((size_t)DBIN * 4);
    int*       perm    = (int*)      carve((size_t)N * 4);
    int*       countsT = (int*)      carve((size_t)NEB * 512 * 4);  // per-block bucket counts
    _Float16*  wp1     = (_Float16*) carve((size_t)IN_CH * 64 * 2);
    _Float16*  wp2     = (_Float16*) carve((size_t)64 * 64 * 2);
    _Float16*  wp3     = (_Float16*) carve((size_t)64 * 64 * 2);

    const int NW8 = (N + 31) / 32;        // aggregate: 8 nodes/wave, 4 waves/block
    const int NBM = (N / 16 + 3) / 4;     // mfma gemm: 16 rows/wave, 4 waves/block

    // ---- W fragment pre-pack (all layers) + zero-init bcnt/dcnt ----
    wpack3_k<<<64, 256, 0, stream>>>(W1, W2, W3, wp1, wp2, wp3, bcnt);

    // ---- CSR build (shared by all 3 layers); atomic-reservation sort ----
    csortA1_k<<<NEB, 256, 0, stream>>>(ei, bcnt, countsT, E);
    bscan_k  <<<1, 512, 0, stream>>>(bcnt, bbase, bcur, NBUCK, E);
    csortA3_k<<<NEB, 256, 0, stream>>>(ei, countsT, bcur, pairs, E);
    csortB2_k<<<NBUCK, 256, 0, stream>>>(pairs, bbase, off, csr, dcnt, N, E, NBUCK);

    // ---- node degree-sort, DESCENDING (LPT: heavy blocks dispatch first) ----
    dscan_k  <<<1, DBIN, 0, stream>>>(dcnt, dcur);
    drank2_k <<<NBUCK, 256, 0, stream>>>(off, dcur, perm, N);

    // ---- Layer 1: IN=128 -> 2x32 concat, relu ----
    gemm_mfma_k<128, 2, false><<<NBM, 256, 0, stream>>>(x, wp1, as1, ad1, hbuf, als, ald, N);
    aggregate_k<2, 1, true>   <<<NW8, 256, 0, stream>>>(hbuf, als, ald, off, csr, perm, b1, obuf, N);

    // ---- Layer 2: 64 -> 2x32 concat, relu ----
    gemm_mfma_k<64, 2, true><<<NBM, 256, 0, stream>>>(obuf, wp2, as2, ad2, hbuf, als, ald, N);
    aggregate_k<2, 1, true> <<<NW8, 256, 0, stream>>>(hbuf, als, ald, off, csr, perm, b2, obuf, N);

    // ---- Layer 3: 64 -> 64, 1 head, mean(=identity), no relu ----
    gemm_mfma_k<64, 1, true><<<NBM, 256, 0, stream>>>(obuf, wp3, as3, ad3, hbuf, als, ald, N);
    aggregate_k<1, 0, false><<<NW8, 256, 0, stream>>>(hbuf, als, ald, off, csr, perm, b3, d_out, N);
}